// Round 3
// baseline (1267.303 us; speedup 1.0000x reference)
//
#include <hip/hip_runtime.h>
#include <math.h>

typedef unsigned short u16;
typedef unsigned int u32;
typedef __attribute__((ext_vector_type(4))) unsigned short u16x4;
typedef __attribute__((ext_vector_type(8))) short bf16x8;
typedef __attribute__((ext_vector_type(4))) float f32x4;

#define B_ 4
#define S_ 2048
#define D_ 1024
#define H_ 16
#define NT (B_*S_)
#define DFF 4096

static __device__ __forceinline__ float bf2f(u16 u) {
    return __uint_as_float(((u32)u) << 16);
}
static __device__ __forceinline__ u16 f2bf(float f) {
    u32 u = __float_as_uint(f);
    u32 r = (u + 0x7fffu + ((u >> 16) & 1u)) >> 16;
    return (u16)r;
}

// ------------------------------------------------- transpose fp32 -> bf16
// out[c][r] = bf16(in[r][c]); R,C multiples of 32. block (32,8)
__global__ void transpose_f2b(const float* __restrict__ in, u16* __restrict__ out,
                              int R, int C) {
    __shared__ float t[32][33];
    int c0 = blockIdx.x * 32, r0 = blockIdx.y * 32;
    int x = threadIdx.x, y = threadIdx.y;
    #pragma unroll
    for (int i = 0; i < 4; i++)
        t[y + i*8][x] = in[(long)(r0 + y + i*8) * C + c0 + x];
    __syncthreads();
    #pragma unroll
    for (int i = 0; i < 4; i++)
        out[(long)(c0 + y + i*8) * R + r0 + x] = f2bf(t[x][y + i*8]);
}

// V bf16 [B*S][D] -> Vt bf16 [B*H][64][S]. grid (S/32, 2, B*H), block (32,8)
__global__ void transpose_v(const u16* __restrict__ V, u16* __restrict__ Vt) {
    __shared__ u16 t[32][33];
    int z = blockIdx.z; int b = z >> 4, h = z & 15;
    int s0 = blockIdx.x * 32, d0 = blockIdx.y * 32;
    int x = threadIdx.x, y = threadIdx.y;
    const u16* in = V + ((long)b * S_ + s0) * D_ + h * 64 + d0;
    #pragma unroll
    for (int i = 0; i < 4; i++)
        t[y + i*8][x] = in[(long)(y + i*8) * D_ + x];
    __syncthreads();
    u16* out = Vt + ((long)z * 64 + d0) * S_ + s0;
    #pragma unroll
    for (int i = 0; i < 4; i++)
        out[(long)(y + i*8) * S_ + x] = t[x][y + i*8];
}

// ------------------------------------------------- layernorm (fp32 in, bf16 out)
__global__ __launch_bounds__(256) void ln_kernel(
    const float* __restrict__ X, const float* __restrict__ alpha,
    const float* __restrict__ beta, u16* __restrict__ Y) {
    int row = blockIdx.x, tid = threadIdx.x;
    float4 xv = ((const float4*)(X + (long)row * D_))[tid];
    float v[4] = {xv.x, xv.y, xv.z, xv.w};
    float s = 0.f, ss = 0.f;
    #pragma unroll
    for (int i = 0; i < 4; i++) { s += v[i]; ss += v[i]*v[i]; }
    #pragma unroll
    for (int off = 32; off >= 1; off >>= 1) {
        s += __shfl_xor(s, off);
        ss += __shfl_xor(ss, off);
    }
    __shared__ float red[8];
    __shared__ float stats[2];
    int w = tid >> 6;
    if ((tid & 63) == 0) { red[w] = s; red[4 + w] = ss; }
    __syncthreads();
    if (tid == 0) {
        float S = red[0] + red[1] + red[2] + red[3];
        float SS = red[4] + red[5] + red[6] + red[7];
        float mean = S * (1.f / D_);
        float var = SS * (1.f / D_) - mean * mean;
        stats[0] = mean; stats[1] = rsqrtf(var + 1e-5f);
    }
    __syncthreads();
    float mean = stats[0], rstd = stats[1];
    float4 av = ((const float4*)alpha)[tid];
    float4 bv = ((const float4*)beta)[tid];
    u16x4 o;
    o[0] = f2bf((v[0] - mean) * rstd * av.x + bv.x);
    o[1] = f2bf((v[1] - mean) * rstd * av.y + bv.y);
    o[2] = f2bf((v[2] - mean) * rstd * av.z + bv.z);
    o[3] = f2bf((v[3] - mean) * rstd * av.w + bv.w);
    *(u16x4*)(Y + (long)row * D_ + tid * 4) = o;
}

// ------------------------------------------------- GEMM (bf16 A, bf16 B^T)
// C[m][n] = sum_k A[m][k]*Bt[n][k] + epilogue. 128x128 tile, BK=64, 4 waves.
// mode 0: store bf16
// mode 1: store fp32 (acc + resid_f32)
// mode 2: store bf16 gelu(acc + bias_f32)
// mode 3: store fp32 (acc + bias_f32 + resid_f32)
#define BM 128
#define BN 128
#define BK 64
#define LDK 72

__global__ __launch_bounds__(256) void gemm_bt(
    const u16* __restrict__ A,
    const u16* __restrict__ Bt0, const u16* __restrict__ Bt1, const u16* __restrict__ Bt2,
    void* __restrict__ C0, void* __restrict__ C1, void* __restrict__ C2,
    int M, int N, int K, int mode,
    const float* __restrict__ bias, const float* __restrict__ resid) {
    const u16* Bt = Bt0; void* C = C0;
    if (blockIdx.z == 1) { Bt = Bt1; C = C1; }
    else if (blockIdx.z == 2) { Bt = Bt2; C = C2; }

    __shared__ __align__(16) u16 Asm[BM * LDK];
    __shared__ __align__(16) u16 Bsm[BN * LDK];

    int tid = threadIdx.x;
    int lane = tid & 63, wave = tid >> 6;
    int l15 = lane & 15, quad = lane >> 4;
    int wm = wave & 1, wn = wave >> 1;
    long tm0 = (long)blockIdx.y * BM, tn0 = (long)blockIdx.x * BN;

    f32x4 acc[4][4] = {};

    for (int k0 = 0; k0 < K; k0 += BK) {
        __syncthreads();
        #pragma unroll
        for (int t = 0; t < 4; t++) {
            int ch = tid + t * 256;
            int row = ch >> 3, cc = ch & 7;
            *(bf16x8*)&Asm[row * LDK + cc * 8] =
                *(const bf16x8*)&A[(tm0 + row) * (long)K + k0 + cc * 8];
            *(bf16x8*)&Bsm[row * LDK + cc * 8] =
                *(const bf16x8*)&Bt[(tn0 + row) * (long)K + k0 + cc * 8];
        }
        __syncthreads();
        #pragma unroll
        for (int ks = 0; ks < 2; ks++) {
            bf16x8 af[4], bfm[4];
            #pragma unroll
            for (int mt = 0; mt < 4; mt++)
                af[mt] = *(const bf16x8*)&Asm[(wm*64 + mt*16 + l15) * LDK + ks*32 + quad*8];
            #pragma unroll
            for (int nt = 0; nt < 4; nt++)
                bfm[nt] = *(const bf16x8*)&Bsm[(wn*64 + nt*16 + l15) * LDK + ks*32 + quad*8];
            #pragma unroll
            for (int mt = 0; mt < 4; mt++)
                #pragma unroll
                for (int nt = 0; nt < 4; nt++)
                    acc[mt][nt] = __builtin_amdgcn_mfma_f32_16x16x32_bf16(
                        af[mt], bfm[nt], acc[mt][nt], 0, 0, 0);
        }
    }

    #pragma unroll
    for (int mt = 0; mt < 4; mt++) {
        #pragma unroll
        for (int nt = 0; nt < 4; nt++) {
            #pragma unroll
            for (int i = 0; i < 4; i++) {
                long r = tm0 + wm*64 + mt*16 + quad*4 + i;
                long cn = tn0 + wn*64 + nt*16 + l15;
                long idx = r * N + cn;
                float val = acc[mt][nt][i];
                if (mode == 0) {
                    ((u16*)C)[idx] = f2bf(val);
                } else if (mode == 1) {
                    ((float*)C)[idx] = val + resid[idx];
                } else if (mode == 2) {
                    val += bias[cn];
                    val = 0.5f * val * (1.0f + erff(val * 0.70710678118654752f));
                    ((u16*)C)[idx] = f2bf(val);
                } else {
                    ((float*)C)[idx] = val + bias[cn] + resid[idx];
                }
            }
        }
    }
}

// ------------------------------------------------- attention (bf16 in/out)
// flash-style, 1 wave = 16 q rows, k-tiles of 32, online softmax.
// ktiles is BLOCK-uniform so __syncthreads() is legal; extra fully-masked
// tiles are no-ops once mrow > -1e30 (tile 0 is always valid).
__global__ __launch_bounds__(256) void attn_kernel(
    const u16* __restrict__ Q, const u16* __restrict__ Kg, const u16* __restrict__ Vt,
    const int* __restrict__ mask, u16* __restrict__ O) {
    __shared__ __align__(16) u16 Pl[4][16 * 32];
    int tid = threadIdx.x;
    int lane = tid & 63, wave = tid >> 6;
    int l15 = lane & 15, quad = lane >> 4;
    int bh = blockIdx.y; int b = bh >> 4, h = bh & 15;
    int q0 = blockIdx.x * 64 + wave * 16;
    long tokBase = (long)b * S_;

    const u16* qptr = Q + (tokBase + q0 + l15) * D_ + h * 64;
    bf16x8 aq0 = *(const bf16x8*)(qptr + quad * 8);
    bf16x8 aq1 = *(const bf16x8*)(qptr + 32 + quad * 8);

    f32x4 o[4] = {};
    float mrow[4], lrow[4];
    #pragma unroll
    for (int i = 0; i < 4; i++) { mrow[i] = -1e30f; lrow[i] = 0.f; }

    u16* Pw = Pl[wave];
    const int* mb = mask + b * S_;
    int ktiles = 2 * blockIdx.x + 2;
    for (int kt = 0; kt < ktiles; kt++) {
        int k0 = kt * 32;
        const u16* kptr = Kg + (tokBase + k0 + l15) * D_ + h * 64;
        bf16x8 kb00 = *(const bf16x8*)(kptr + quad * 8);
        bf16x8 kb01 = *(const bf16x8*)(kptr + 32 + quad * 8);
        bf16x8 kb10 = *(const bf16x8*)(kptr + 16 * D_ + quad * 8);
        bf16x8 kb11 = *(const bf16x8*)(kptr + 16 * D_ + 32 + quad * 8);

        f32x4 s0 = {0.f, 0.f, 0.f, 0.f}, s1 = {0.f, 0.f, 0.f, 0.f};
        s0 = __builtin_amdgcn_mfma_f32_16x16x32_bf16(aq0, kb00, s0, 0, 0, 0);
        s0 = __builtin_amdgcn_mfma_f32_16x16x32_bf16(aq1, kb01, s0, 0, 0, 0);
        s1 = __builtin_amdgcn_mfma_f32_16x16x32_bf16(aq0, kb10, s1, 0, 0, 0);
        s1 = __builtin_amdgcn_mfma_f32_16x16x32_bf16(aq1, kb11, s1, 0, 0, 0);

        int kc0 = k0 + l15, kc1 = k0 + 16 + l15;
        bool mk0 = mb[kc0] != 0, mk1 = mb[kc1] != 0;
        #pragma unroll
        for (int i = 0; i < 4; i++) {
            int qq = q0 + quad * 4 + i;
            float v0 = (kc0 <= qq && mk0) ? s0[i] * 0.125f : -1e30f;
            float v1 = (kc1 <= qq && mk1) ? s1[i] * 0.125f : -1e30f;
            float mt_ = fmaxf(v0, v1);
            #pragma unroll
            for (int mm = 1; mm < 16; mm <<= 1) mt_ = fmaxf(mt_, __shfl_xor(mt_, mm));
            float mnew = fmaxf(mrow[i], mt_);
            float alpha = __expf(mrow[i] - mnew);
            float p0 = __expf(v0 - mnew);
            float p1 = __expf(v1 - mnew);
            float ps = p0 + p1;
            #pragma unroll
            for (int mm = 1; mm < 16; mm <<= 1) ps += __shfl_xor(ps, mm);
            lrow[i] = lrow[i] * alpha + ps;
            mrow[i] = mnew;
            #pragma unroll
            for (int nt = 0; nt < 4; nt++) o[nt][i] *= alpha;
            Pw[(quad * 4 + i) * 32 + l15] = f2bf(p0);
            Pw[(quad * 4 + i) * 32 + 16 + l15] = f2bf(p1);
        }
        __syncthreads();
        bf16x8 ap = *(const bf16x8*)&Pw[l15 * 32 + quad * 8];
        const u16* vptr = Vt + ((long)bh * 64 + l15) * S_ + k0 + quad * 8;
        #pragma unroll
        for (int nt = 0; nt < 4; nt++) {
            bf16x8 vb = *(const bf16x8*)(vptr + (long)nt * 16 * S_);
            o[nt] = __builtin_amdgcn_mfma_f32_16x16x32_bf16(ap, vb, o[nt], 0, 0, 0);
        }
        __syncthreads();
    }
    #pragma unroll
    for (int nt = 0; nt < 4; nt++) {
        #pragma unroll
        for (int i = 0; i < 4; i++) {
            long r = tokBase + q0 + quad * 4 + i;
            O[r * D_ + h * 64 + nt * 16 + l15] = f2bf(o[nt][i] / lrow[i]);
        }
    }
}

// ------------------------------------------------- launch
extern "C" void kernel_launch(void* const* d_in, const int* in_sizes, int n_in,
                              void* d_out, int out_size, void* d_ws, size_t ws_size,
                              hipStream_t stream) {
    const float* x    = (const float*)d_in[0];
    const int*   am   = (const int*)d_in[1];
    const float* ln1a = (const float*)d_in[2];
    const float* ln1b = (const float*)d_in[3];
    const float* ln2a = (const float*)d_in[4];
    const float* ln2b = (const float*)d_in[5];
    const float* wq   = (const float*)d_in[6];
    const float* wk   = (const float*)d_in[7];
    const float* wv   = (const float*)d_in[8];
    const float* wo   = (const float*)d_in[9];
    const float* w1   = (const float*)d_in[10];
    const float* b1   = (const float*)d_in[11];
    const float* w2   = (const float*)d_in[12];
    const float* b2   = (const float*)d_in[13];
    float* out = (float*)d_out;

    // Workspace: 72 MB total, liveness-overlapped 16MB slots.
    char* ws = (char*)d_ws;
    const size_t MB16 = (size_t)16 * 1024 * 1024;
    u16* y1      = (u16*)(ws + 0 * MB16);   // LN1 out; dead after QKV -> y2
    u16* q       = (u16*)(ws + 1 * MB16);   // dead after attn -> w1t/w2t
    u16* k       = (u16*)(ws + 2 * MB16);   // dead after attn -> h_chunk
    u16* v       = (u16*)(ws + 3 * MB16);   // dead after transpose_v -> ctx
    u16* wqt     = (u16*)(ws + 4 * MB16 + 0 * (size_t)D_ * D_ * 2);
    u16* wkt     = (u16*)(ws + 4 * MB16 + 1 * (size_t)D_ * D_ * 2);
    u16* wvt     = (u16*)(ws + 4 * MB16 + 2 * (size_t)D_ * D_ * 2);
    u16* wot     = (u16*)(ws + 4 * MB16 + 3 * (size_t)D_ * D_ * 2);
    u16* y2      = y1;                       // after QKV
    u16* w1t     = q;                        // after attn (8 MB)
    u16* w2t     = q + (size_t)D_ * DFF;     // after attn (8 MB)
    u16* h_chunk = k;                        // after attn (16 MB)
    u16* ctx     = v;                        // after transpose_v
    // d_out (32 MB fp32) doubles as scratch under stream ordering:
    u16*   vt  = (u16*)d_out;                // 16 MB; dead after attn
    float* x1f = out;                        // x + ctx@Wo, written after attn

    dim3 tb(32, 8);
    // fp32 -> bf16 transposed weights (QKV + Wo up front)
    transpose_f2b<<<dim3(D_/32, D_/32), tb, 0, stream>>>(wq, wqt, D_, D_);
    transpose_f2b<<<dim3(D_/32, D_/32), tb, 0, stream>>>(wk, wkt, D_, D_);
    transpose_f2b<<<dim3(D_/32, D_/32), tb, 0, stream>>>(wv, wvt, D_, D_);
    transpose_f2b<<<dim3(D_/32, D_/32), tb, 0, stream>>>(wo, wot, D_, D_);

    ln_kernel<<<NT, 256, 0, stream>>>(x, ln1a, ln1b, y1);

    gemm_bt<<<dim3(D_/BN, NT/BM, 3), 256, 0, stream>>>(
        y1, wqt, wkt, wvt, q, k, v, NT, D_, D_, 0, nullptr, nullptr);

    transpose_v<<<dim3(S_/32, 2, B_*H_), tb, 0, stream>>>(v, vt);

    attn_kernel<<<dim3(S_/64, B_*H_), 256, 0, stream>>>(q, k, vt, am, ctx);

    // x1f = x + ctx @ Wo   (fp32 store into d_out)
    gemm_bt<<<dim3(D_/BN, NT/BM, 1), 256, 0, stream>>>(
        ctx, wot, wot, wot, x1f, x1f, x1f, NT, D_, D_, 1, nullptr, x);

    // FFN weights into the now-dead q slot
    transpose_f2b<<<dim3(DFF/32, D_/32), tb, 0, stream>>>(w1, w1t, D_, DFF);
    transpose_f2b<<<dim3(D_/32, DFF/32), tb, 0, stream>>>(w2, w2t, DFF, D_);

    ln_kernel<<<NT, 256, 0, stream>>>(x1f, ln2a, ln2b, y2);

    // FFN, M-chunked (4 x 2048 rows) so h needs only one 16MB slot
    for (int mc = 0; mc < 4; mc++) {
        long m0 = (long)mc * 2048;
        gemm_bt<<<dim3(DFF/BN, 2048/BM, 1), 256, 0, stream>>>(
            y2 + m0 * D_, w1t, w1t, w1t, h_chunk, h_chunk, h_chunk,
            2048, DFF, D_, 2, b1, nullptr);
        gemm_bt<<<dim3(D_/BN, 2048/BM, 1), 256, 0, stream>>>(
            h_chunk, w2t, w2t, w2t, out + m0 * D_, out + m0 * D_, out + m0 * D_,
            2048, D_, DFF, 3, b2, x1f + m0 * D_);
    }
}

// Round 4
// 984.615 us; speedup vs baseline: 1.2871x; 1.2871x over previous
//
#include <hip/hip_runtime.h>
#include <math.h>

typedef unsigned short u16;
typedef unsigned int u32;
typedef __attribute__((ext_vector_type(4))) unsigned short u16x4;
typedef __attribute__((ext_vector_type(8))) short bf16x8;
typedef __attribute__((ext_vector_type(4))) float f32x4;

#define B_ 4
#define S_ 2048
#define D_ 1024
#define H_ 16
#define NT (B_*S_)
#define DFF 4096

static __device__ __forceinline__ float bf2f(u16 u) {
    return __uint_as_float(((u32)u) << 16);
}
static __device__ __forceinline__ u16 f2bf(float f) {
    u32 u = __float_as_uint(f);
    u32 r = (u + 0x7fffu + ((u >> 16) & 1u)) >> 16;
    return (u16)r;
}
// async 16B/lane global->LDS (LDS dest = wave-uniform base + lane*16)
static __device__ __forceinline__ void gload_lds16(const void* g, void* l) {
    __builtin_amdgcn_global_load_lds(
        (const __attribute__((address_space(1))) void*)g,
        (__attribute__((address_space(3))) void*)l, 16, 0, 0);
}

// ------------------------------------------------- transpose fp32 -> bf16
__global__ void transpose_f2b(const float* __restrict__ in, u16* __restrict__ out,
                              int R, int C) {
    __shared__ float t[32][33];
    int c0 = blockIdx.x * 32, r0 = blockIdx.y * 32;
    int x = threadIdx.x, y = threadIdx.y;
    #pragma unroll
    for (int i = 0; i < 4; i++)
        t[y + i*8][x] = in[(long)(r0 + y + i*8) * C + c0 + x];
    __syncthreads();
    #pragma unroll
    for (int i = 0; i < 4; i++)
        out[(long)(c0 + y + i*8) * R + r0 + x] = f2bf(t[x][y + i*8]);
}

// V bf16 [B*S][D] -> Vt bf16 [B*H][64][S]. grid (S/32, 2, B*H), block (32,8)
__global__ void transpose_v(const u16* __restrict__ V, u16* __restrict__ Vt) {
    __shared__ u16 t[32][33];
    int z = blockIdx.z; int b = z >> 4, h = z & 15;
    int s0 = blockIdx.x * 32, d0 = blockIdx.y * 32;
    int x = threadIdx.x, y = threadIdx.y;
    const u16* in = V + ((long)b * S_ + s0) * D_ + h * 64 + d0;
    #pragma unroll
    for (int i = 0; i < 4; i++)
        t[y + i*8][x] = in[(long)(y + i*8) * D_ + x];
    __syncthreads();
    u16* out = Vt + ((long)z * 64 + d0) * S_ + s0;
    #pragma unroll
    for (int i = 0; i < 4; i++)
        out[(long)(y + i*8) * S_ + x] = t[x][y + i*8];
}

// ------------------------------------------------- layernorm (fp32 in, bf16 out)
__global__ __launch_bounds__(256) void ln_kernel(
    const float* __restrict__ X, const float* __restrict__ alpha,
    const float* __restrict__ beta, u16* __restrict__ Y) {
    int row = blockIdx.x, tid = threadIdx.x;
    float4 xv = ((const float4*)(X + (long)row * D_))[tid];
    float v[4] = {xv.x, xv.y, xv.z, xv.w};
    float s = 0.f, ss = 0.f;
    #pragma unroll
    for (int i = 0; i < 4; i++) { s += v[i]; ss += v[i]*v[i]; }
    #pragma unroll
    for (int off = 32; off >= 1; off >>= 1) {
        s += __shfl_xor(s, off);
        ss += __shfl_xor(ss, off);
    }
    __shared__ float red[8];
    __shared__ float stats[2];
    int w = tid >> 6;
    if ((tid & 63) == 0) { red[w] = s; red[4 + w] = ss; }
    __syncthreads();
    if (tid == 0) {
        float S = red[0] + red[1] + red[2] + red[3];
        float SS = red[4] + red[5] + red[6] + red[7];
        float mean = S * (1.f / D_);
        float var = SS * (1.f / D_) - mean * mean;
        stats[0] = mean; stats[1] = rsqrtf(var + 1e-5f);
    }
    __syncthreads();
    float mean = stats[0], rstd = stats[1];
    float4 av = ((const float4*)alpha)[tid];
    float4 bv = ((const float4*)beta)[tid];
    u16x4 o;
    o[0] = f2bf((v[0] - mean) * rstd * av.x + bv.x);
    o[1] = f2bf((v[1] - mean) * rstd * av.y + bv.y);
    o[2] = f2bf((v[2] - mean) * rstd * av.z + bv.z);
    o[3] = f2bf((v[3] - mean) * rstd * av.w + bv.w);
    *(u16x4*)(Y + (long)row * D_ + tid * 4) = o;
}

// ------------------------------------------------- GEMM (bf16 A, bf16 B^T)
// m97 recipe: unpadded [row][64] LDS tiles staged via global_load_lds x16.
// mode 0: bf16 store; 1: fp32 acc+resid; 2: bf16 gelu(acc+bias); 3: fp32 acc+bias+resid
#define BM 128
#define BN 128
#define BK 64

__global__ __launch_bounds__(256, 2) void gemm_bt(
    const u16* __restrict__ A,
    const u16* __restrict__ Bt0, const u16* __restrict__ Bt1, const u16* __restrict__ Bt2,
    void* __restrict__ C0, void* __restrict__ C1, void* __restrict__ C2,
    int M, int N, int K, int mode,
    const float* __restrict__ bias, const float* __restrict__ resid) {
    const u16* Bt = Bt0; void* C = C0;
    if (blockIdx.z == 1) { Bt = Bt1; C = C1; }
    else if (blockIdx.z == 2) { Bt = Bt2; C = C2; }

    __shared__ __align__(16) u16 Asm[BM * BK];
    __shared__ __align__(16) u16 Bsm[BN * BK];

    int tid = threadIdx.x;
    int lane = tid & 63, wave = tid >> 6;
    int l15 = lane & 15, quad = lane >> 4;
    int wm = wave & 1, wn = wave >> 1;
    long tm0 = (long)blockIdx.y * BM, tn0 = (long)blockIdx.x * BN;

    int srow = lane >> 3;          // 0..7 within chunk
    int scol = (lane & 7) * 8;     // u16 col offset

    f32x4 acc[4][4] = {};

    for (int k0 = 0; k0 < K; k0 += BK) {
        __syncthreads();
        #pragma unroll
        for (int c = 0; c < 4; c++) {
            int chunk = wave * 4 + c;          // 0..15
            int row = chunk * 8 + srow;        // 0..127
            gload_lds16(&A[(tm0 + row) * (long)K + k0 + scol], &Asm[chunk * 512]);
            gload_lds16(&Bt[(tn0 + row) * (long)K + k0 + scol], &Bsm[chunk * 512]);
        }
        __syncthreads();   // drains vmcnt(0): LDS tiles complete
        #pragma unroll
        for (int ks = 0; ks < 2; ks++) {
            bf16x8 af[4], bfm[4];
            #pragma unroll
            for (int mt = 0; mt < 4; mt++)
                af[mt] = *(const bf16x8*)&Asm[(wm*64 + mt*16 + l15) * BK + ks*32 + quad*8];
            #pragma unroll
            for (int nt = 0; nt < 4; nt++)
                bfm[nt] = *(const bf16x8*)&Bsm[(wn*64 + nt*16 + l15) * BK + ks*32 + quad*8];
            #pragma unroll
            for (int mt = 0; mt < 4; mt++)
                #pragma unroll
                for (int nt = 0; nt < 4; nt++)
                    acc[mt][nt] = __builtin_amdgcn_mfma_f32_16x16x32_bf16(
                        af[mt], bfm[nt], acc[mt][nt], 0, 0, 0);
        }
    }

    #pragma unroll
    for (int mt = 0; mt < 4; mt++) {
        #pragma unroll
        for (int nt = 0; nt < 4; nt++) {
            #pragma unroll
            for (int i = 0; i < 4; i++) {
                long r = tm0 + wm*64 + mt*16 + quad*4 + i;
                long cn = tn0 + wn*64 + nt*16 + l15;
                long idx = r * N + cn;
                float val = acc[mt][nt][i];
                if (mode == 0) {
                    ((u16*)C)[idx] = f2bf(val);
                } else if (mode == 1) {
                    ((float*)C)[idx] = val + resid[idx];
                } else if (mode == 2) {
                    val += bias[cn];
                    val = 0.5f * val * (1.0f + erff(val * 0.70710678118654752f));
                    ((u16*)C)[idx] = f2bf(val);
                } else {
                    ((float*)C)[idx] = val + bias[cn] + resid[idx];
                }
            }
        }
    }
}

// ------------------------------------------------- attention
// Block = 128 q rows (4 waves x 32q), k-tiles of 64, K/Vt staged in LDS once
// per block. Per-wave-private P round-trip fenced with lgkmcnt (no barrier).
#define ALDK 80   // 160B row stride: 16B-aligned for b128, moderate conflicts

__global__ __launch_bounds__(256, 3) void attn_kernel(
    const u16* __restrict__ Q, const u16* __restrict__ Kg, const u16* __restrict__ Vt,
    const int* __restrict__ mask, u16* __restrict__ O) {
    __shared__ __align__(16) u16 Ksm[64 * ALDK];
    __shared__ __align__(16) u16 Vsm[64 * ALDK];
    __shared__ __align__(16) u16 Psm[4][32 * ALDK];
    int tid = threadIdx.x;
    int lane = tid & 63, wave = tid >> 6;
    int l15 = lane & 15, quad = lane >> 4;
    int bh = blockIdx.y; int b = bh >> 4, h = bh & 15;
    int q0 = blockIdx.x * 128 + wave * 32;
    long tokBase = (long)b * S_;

    bf16x8 aq[2][2];
    #pragma unroll
    for (int mt = 0; mt < 2; mt++) {
        const u16* qptr = Q + (tokBase + q0 + mt*16 + l15) * D_ + h * 64;
        aq[mt][0] = *(const bf16x8*)(qptr + quad * 8);
        aq[mt][1] = *(const bf16x8*)(qptr + 32 + quad * 8);
    }

    f32x4 o[2][4] = {};
    float mrow[2][4], lrow[2][4];
    #pragma unroll
    for (int mt = 0; mt < 2; mt++)
        #pragma unroll
        for (int i = 0; i < 4; i++) { mrow[mt][i] = -1e30f; lrow[mt][i] = 0.f; }

    int srow = tid >> 3;           // 0..31
    int scol = (tid & 7) * 8;
    u16* Pw = Psm[wave];
    const int* mb = mask + b * S_;
    int ktiles = 2 * blockIdx.x + 2;   // block-uniform causal bound

    for (int kt = 0; kt < ktiles; kt++) {
        int k0 = kt * 64;
        __syncthreads();   // previous tile's K/V reads done
        #pragma unroll
        for (int p = 0; p < 2; p++) {
            int r = srow + p * 32;
            *(bf16x8*)&Ksm[r * ALDK + scol] =
                *(const bf16x8*)&Kg[(tokBase + k0 + r) * D_ + h * 64 + scol];
            *(bf16x8*)&Vsm[r * ALDK + scol] =
                *(const bf16x8*)&Vt[((long)bh * 64 + r) * S_ + k0 + scol];
        }
        __syncthreads();   // tiles visible to all waves

        f32x4 s[2][4] = {};
        #pragma unroll
        for (int nt = 0; nt < 4; nt++) {
            bf16x8 kb0 = *(const bf16x8*)&Ksm[(nt*16 + l15) * ALDK + quad*8];
            bf16x8 kb1 = *(const bf16x8*)&Ksm[(nt*16 + l15) * ALDK + 32 + quad*8];
            s[0][nt] = __builtin_amdgcn_mfma_f32_16x16x32_bf16(aq[0][0], kb0, s[0][nt], 0,0,0);
            s[0][nt] = __builtin_amdgcn_mfma_f32_16x16x32_bf16(aq[0][1], kb1, s[0][nt], 0,0,0);
            s[1][nt] = __builtin_amdgcn_mfma_f32_16x16x32_bf16(aq[1][0], kb0, s[1][nt], 0,0,0);
            s[1][nt] = __builtin_amdgcn_mfma_f32_16x16x32_bf16(aq[1][1], kb1, s[1][nt], 0,0,0);
        }

        int mk = 0;
        #pragma unroll
        for (int nt = 0; nt < 4; nt++)
            if (mb[k0 + nt*16 + l15] != 0) mk |= (1 << nt);

        #pragma unroll
        for (int mt = 0; mt < 2; mt++) {
            #pragma unroll
            for (int i = 0; i < 4; i++) {
                int qq = q0 + mt*16 + quad*4 + i;
                float v[4], vmax = -1e30f;
                #pragma unroll
                for (int nt = 0; nt < 4; nt++) {
                    int kc = k0 + nt*16 + l15;
                    v[nt] = (kc <= qq && ((mk >> nt) & 1)) ? s[mt][nt][i] * 0.125f : -1e30f;
                    vmax = fmaxf(vmax, v[nt]);
                }
                #pragma unroll
                for (int mm = 1; mm < 16; mm <<= 1) vmax = fmaxf(vmax, __shfl_xor(vmax, mm));
                float mnew = fmaxf(mrow[mt][i], vmax);
                float alpha = __expf(mrow[mt][i] - mnew);
                float ps = 0.f;
                #pragma unroll
                for (int nt = 0; nt < 4; nt++) {
                    float p = __expf(v[nt] - mnew);
                    ps += p;
                    Pw[(mt*16 + quad*4 + i) * ALDK + nt*16 + l15] = f2bf(p);
                }
                #pragma unroll
                for (int mm = 1; mm < 16; mm <<= 1) ps += __shfl_xor(ps, mm);
                lrow[mt][i] = lrow[mt][i] * alpha + ps;
                mrow[mt][i] = mnew;
                #pragma unroll
                for (int d = 0; d < 4; d++) o[mt][d][i] *= alpha;
            }
        }
        // same-wave P write -> read: HW wait + compiler fence (P is wave-private)
        asm volatile("s_waitcnt lgkmcnt(0)" ::: "memory");
        #pragma unroll
        for (int half = 0; half < 2; half++) {
            bf16x8 ap0 = *(const bf16x8*)&Pw[l15 * ALDK + half*32 + quad*8];
            bf16x8 ap1 = *(const bf16x8*)&Pw[(16 + l15) * ALDK + half*32 + quad*8];
            #pragma unroll
            for (int d = 0; d < 4; d++) {
                bf16x8 vb = *(const bf16x8*)&Vsm[(d*16 + l15) * ALDK + half*32 + quad*8];
                o[0][d] = __builtin_amdgcn_mfma_f32_16x16x32_bf16(ap0, vb, o[0][d], 0,0,0);
                o[1][d] = __builtin_amdgcn_mfma_f32_16x16x32_bf16(ap1, vb, o[1][d], 0,0,0);
            }
        }
    }

    #pragma unroll
    for (int mt = 0; mt < 2; mt++) {
        #pragma unroll
        for (int i = 0; i < 4; i++) {
            float inv = 1.f / lrow[mt][i];
            long r = tokBase + q0 + mt*16 + quad*4 + i;
            #pragma unroll
            for (int d = 0; d < 4; d++)
                O[r * D_ + h*64 + d*16 + l15] = f2bf(o[mt][d][i] * inv);
        }
    }
}

// ------------------------------------------------- launch
extern "C" void kernel_launch(void* const* d_in, const int* in_sizes, int n_in,
                              void* d_out, int out_size, void* d_ws, size_t ws_size,
                              hipStream_t stream) {
    const float* x    = (const float*)d_in[0];
    const int*   am   = (const int*)d_in[1];
    const float* ln1a = (const float*)d_in[2];
    const float* ln1b = (const float*)d_in[3];
    const float* ln2a = (const float*)d_in[4];
    const float* ln2b = (const float*)d_in[5];
    const float* wq   = (const float*)d_in[6];
    const float* wk   = (const float*)d_in[7];
    const float* wv   = (const float*)d_in[8];
    const float* wo   = (const float*)d_in[9];
    const float* w1   = (const float*)d_in[10];
    const float* b1   = (const float*)d_in[11];
    const float* w2   = (const float*)d_in[12];
    const float* b2   = (const float*)d_in[13];
    float* out = (float*)d_out;

    // Workspace: 72 MB, liveness-overlapped 16MB slots.
    char* ws = (char*)d_ws;
    const size_t MB16 = (size_t)16 * 1024 * 1024;
    u16* y1      = (u16*)(ws + 0 * MB16);   // LN1 out -> y2 (LN2 out)
    u16* q       = (u16*)(ws + 1 * MB16);   // q -> w1t/w2t
    u16* k       = (u16*)(ws + 2 * MB16);   // k -> h (slots 2+3)
    u16* v       = (u16*)(ws + 3 * MB16);   // v -> ctx -> h
    u16* wqt     = (u16*)(ws + 4 * MB16 + 0 * (size_t)D_ * D_ * 2);
    u16* wkt     = (u16*)(ws + 4 * MB16 + 1 * (size_t)D_ * D_ * 2);
    u16* wvt     = (u16*)(ws + 4 * MB16 + 2 * (size_t)D_ * D_ * 2);
    u16* wot     = (u16*)(ws + 4 * MB16 + 3 * (size_t)D_ * D_ * 2);
    u16* y2      = y1;                       // after QKV
    u16* w1t     = q;                        // after attn (8 MB)
    u16* w2t     = q + (size_t)D_ * DFF;     // after attn (8 MB)
    u16* h_chunk = k;                        // after Wo GEMM: 32 MB (slots 2+3)
    u16* ctx     = v;                        // after transpose_v
    u16*   vt  = (u16*)d_out;                // d_out scratch; dead after attn
    float* x1f = out;                        // x + ctx@Wo

    dim3 tb(32, 8);
    transpose_f2b<<<dim3(D_/32, D_/32), tb, 0, stream>>>(wq, wqt, D_, D_);
    transpose_f2b<<<dim3(D_/32, D_/32), tb, 0, stream>>>(wk, wkt, D_, D_);
    transpose_f2b<<<dim3(D_/32, D_/32), tb, 0, stream>>>(wv, wvt, D_, D_);
    transpose_f2b<<<dim3(D_/32, D_/32), tb, 0, stream>>>(wo, wot, D_, D_);

    ln_kernel<<<NT, 256, 0, stream>>>(x, ln1a, ln1b, y1);

    gemm_bt<<<dim3(D_/BN, NT/BM, 3), 256, 0, stream>>>(
        y1, wqt, wkt, wvt, q, k, v, NT, D_, D_, 0, nullptr, nullptr);

    transpose_v<<<dim3(S_/32, 2, B_*H_), tb, 0, stream>>>(v, vt);

    attn_kernel<<<dim3(S_/128, B_*H_), 256, 0, stream>>>(q, k, vt, am, ctx);

    gemm_bt<<<dim3(D_/BN, NT/BM, 1), 256, 0, stream>>>(
        ctx, wot, wot, wot, x1f, x1f, x1f, NT, D_, D_, 1, nullptr, x);

    transpose_f2b<<<dim3(DFF/32, D_/32), tb, 0, stream>>>(w1, w1t, D_, DFF);
    transpose_f2b<<<dim3(D_/32, DFF/32), tb, 0, stream>>>(w2, w2t, DFF, D_);

    ln_kernel<<<NT, 256, 0, stream>>>(x1f, ln2a, ln2b, y2);

    // FFN, 2 chunks of 4096 rows (h: 32MB in slots 2+3)
    for (int mc = 0; mc < 2; mc++) {
        long m0 = (long)mc * 4096;
        gemm_bt<<<dim3(DFF/BN, 4096/BM, 1), 256, 0, stream>>>(
            y2 + m0 * D_, w1t, w1t, w1t, h_chunk, h_chunk, h_chunk,
            4096, DFF, D_, 2, b1, nullptr);
        gemm_bt<<<dim3(D_/BN, 4096/BM, 1), 256, 0, stream>>>(
            h_chunk, w2t, w2t, w2t, out + m0 * D_, out + m0 * D_, out + m0 * D_,
            4096, D_, DFF, 3, b2, x1f + m0 * D_);
    }
}

// Round 5
// 830.099 us; speedup vs baseline: 1.5267x; 1.1861x over previous
//
#include <hip/hip_runtime.h>
#include <math.h>

typedef unsigned short u16;
typedef unsigned int u32;
typedef __attribute__((ext_vector_type(4))) unsigned short u16x4;
typedef __attribute__((ext_vector_type(8))) short bf16x8;
typedef __attribute__((ext_vector_type(4))) float f32x4;

#define B_ 4
#define S_ 2048
#define D_ 1024
#define H_ 16
#define NT (B_*S_)
#define DFF 4096

static __device__ __forceinline__ float bf2f(u16 u) {
    return __uint_as_float(((u32)u) << 16);
}
static __device__ __forceinline__ u16 f2bf(float f) {
    u32 u = __float_as_uint(f);
    u32 r = (u + 0x7fffu + ((u >> 16) & 1u)) >> 16;
    return (u16)r;
}
// async 16B/lane global->LDS (LDS dest = wave-uniform base + lane*16)
static __device__ __forceinline__ void gload_lds16(const void* g, void* l) {
    __builtin_amdgcn_global_load_lds(
        (const __attribute__((address_space(1))) void*)g,
        (__attribute__((address_space(3))) void*)l, 16, 0, 0);
}

// ------------------------------------------------- transpose fp32 -> bf16
__global__ void transpose_f2b(const float* __restrict__ in, u16* __restrict__ out,
                              int R, int C) {
    __shared__ float t[32][33];
    int c0 = blockIdx.x * 32, r0 = blockIdx.y * 32;
    int x = threadIdx.x, y = threadIdx.y;
    #pragma unroll
    for (int i = 0; i < 4; i++)
        t[y + i*8][x] = in[(long)(r0 + y + i*8) * C + c0 + x];
    __syncthreads();
    #pragma unroll
    for (int i = 0; i < 4; i++)
        out[(long)(c0 + y + i*8) * R + r0 + x] = f2bf(t[x][y + i*8]);
}

// V bf16 [B*S][D] -> Vt bf16 [B*H][64][S]. grid (S/32, 2, B*H), block (32,8)
__global__ void transpose_v(const u16* __restrict__ V, u16* __restrict__ Vt) {
    __shared__ u16 t[32][33];
    int z = blockIdx.z; int b = z >> 4, h = z & 15;
    int s0 = blockIdx.x * 32, d0 = blockIdx.y * 32;
    int x = threadIdx.x, y = threadIdx.y;
    const u16* in = V + ((long)b * S_ + s0) * D_ + h * 64 + d0;
    #pragma unroll
    for (int i = 0; i < 4; i++)
        t[y + i*8][x] = in[(long)(y + i*8) * D_ + x];
    __syncthreads();
    u16* out = Vt + ((long)z * 64 + d0) * S_ + s0;
    #pragma unroll
    for (int i = 0; i < 4; i++)
        out[(long)(y + i*8) * S_ + x] = t[x][y + i*8];
}

// ------------------------------------------------- layernorm (fp32 in, bf16 out)
__global__ __launch_bounds__(256) void ln_kernel(
    const float* __restrict__ X, const float* __restrict__ alpha,
    const float* __restrict__ beta, u16* __restrict__ Y) {
    int row = blockIdx.x, tid = threadIdx.x;
    float4 xv = ((const float4*)(X + (long)row * D_))[tid];
    float v[4] = {xv.x, xv.y, xv.z, xv.w};
    float s = 0.f, ss = 0.f;
    #pragma unroll
    for (int i = 0; i < 4; i++) { s += v[i]; ss += v[i]*v[i]; }
    #pragma unroll
    for (int off = 32; off >= 1; off >>= 1) {
        s += __shfl_xor(s, off);
        ss += __shfl_xor(ss, off);
    }
    __shared__ float red[8];
    __shared__ float stats[2];
    int w = tid >> 6;
    if ((tid & 63) == 0) { red[w] = s; red[4 + w] = ss; }
    __syncthreads();
    if (tid == 0) {
        float S = red[0] + red[1] + red[2] + red[3];
        float SS = red[4] + red[5] + red[6] + red[7];
        float mean = S * (1.f / D_);
        float var = SS * (1.f / D_) - mean * mean;
        stats[0] = mean; stats[1] = rsqrtf(var + 1e-5f);
    }
    __syncthreads();
    float mean = stats[0], rstd = stats[1];
    float4 av = ((const float4*)alpha)[tid];
    float4 bv = ((const float4*)beta)[tid];
    u16x4 o;
    o[0] = f2bf((v[0] - mean) * rstd * av.x + bv.x);
    o[1] = f2bf((v[1] - mean) * rstd * av.y + bv.y);
    o[2] = f2bf((v[2] - mean) * rstd * av.z + bv.z);
    o[3] = f2bf((v[3] - mean) * rstd * av.w + bv.w);
    *(u16x4*)(Y + (long)row * D_ + tid * 4) = o;
}

// ------------------------------------------------- GEMM (bf16 A, bf16 B^T)
// m97 recipe: unpadded [row][64] LDS tiles staged via global_load_lds x16.
// mode 0: bf16 store; 1: fp32 acc+resid; 2: bf16 gelu(acc+bias); 3: fp32 acc+bias+resid
#define BM 128
#define BN 128
#define BK 64

__global__ __launch_bounds__(256, 2) void gemm_bt(
    const u16* __restrict__ A,
    const u16* __restrict__ Bt0, const u16* __restrict__ Bt1, const u16* __restrict__ Bt2,
    void* __restrict__ C0, void* __restrict__ C1, void* __restrict__ C2,
    int M, int N, int K, int mode,
    const float* __restrict__ bias, const float* __restrict__ resid) {
    const u16* Bt = Bt0; void* C = C0;
    if (blockIdx.z == 1) { Bt = Bt1; C = C1; }
    else if (blockIdx.z == 2) { Bt = Bt2; C = C2; }

    __shared__ __align__(16) u16 Asm[BM * BK];
    __shared__ __align__(16) u16 Bsm[BN * BK];

    int tid = threadIdx.x;
    int lane = tid & 63, wave = tid >> 6;
    int l15 = lane & 15, quad = lane >> 4;
    int wm = wave & 1, wn = wave >> 1;
    long tm0 = (long)blockIdx.y * BM, tn0 = (long)blockIdx.x * BN;

    int srow = lane >> 3;          // 0..7 within chunk
    int scol = (lane & 7) * 8;     // u16 col offset

    f32x4 acc[4][4] = {};

    for (int k0 = 0; k0 < K; k0 += BK) {
        __syncthreads();
        #pragma unroll
        for (int c = 0; c < 4; c++) {
            int chunk = wave * 4 + c;          // 0..15
            int row = chunk * 8 + srow;        // 0..127
            gload_lds16(&A[(tm0 + row) * (long)K + k0 + scol], &Asm[chunk * 512]);
            gload_lds16(&Bt[(tn0 + row) * (long)K + k0 + scol], &Bsm[chunk * 512]);
        }
        __syncthreads();   // drains vmcnt(0): LDS tiles complete
        #pragma unroll
        for (int ks = 0; ks < 2; ks++) {
            bf16x8 af[4], bfm[4];
            #pragma unroll
            for (int mt = 0; mt < 4; mt++)
                af[mt] = *(const bf16x8*)&Asm[(wm*64 + mt*16 + l15) * BK + ks*32 + quad*8];
            #pragma unroll
            for (int nt = 0; nt < 4; nt++)
                bfm[nt] = *(const bf16x8*)&Bsm[(wn*64 + nt*16 + l15) * BK + ks*32 + quad*8];
            #pragma unroll
            for (int mt = 0; mt < 4; mt++)
                #pragma unroll
                for (int nt = 0; nt < 4; nt++)
                    acc[mt][nt] = __builtin_amdgcn_mfma_f32_16x16x32_bf16(
                        af[mt], bfm[nt], acc[mt][nt], 0, 0, 0);
        }
    }

    #pragma unroll
    for (int mt = 0; mt < 4; mt++) {
        #pragma unroll
        for (int nt = 0; nt < 4; nt++) {
            #pragma unroll
            for (int i = 0; i < 4; i++) {
                long r = tm0 + wm*64 + mt*16 + quad*4 + i;
                long cn = tn0 + wn*64 + nt*16 + l15;
                long idx = r * N + cn;
                float val = acc[mt][nt][i];
                if (mode == 0) {
                    ((u16*)C)[idx] = f2bf(val);
                } else if (mode == 1) {
                    ((float*)C)[idx] = val + resid[idx];
                } else if (mode == 2) {
                    val += bias[cn];
                    val = 0.5f * val * (1.0f + erff(val * 0.70710678118654752f));
                    ((u16*)C)[idx] = f2bf(val);
                } else {
                    ((float*)C)[idx] = val + bias[cn] + resid[idx];
                }
            }
        }
    }
}

// ------------------------------------------------- attention (wave-autonomous)
// One wave = one 32-row q-tile; k-tiles of 64. K/V fragments loaded straight
// from global into registers (no block cooperation, ZERO __syncthreads).
// Row-sums of P come free from an extra MFMA with an all-ones B operand.
// Softmax runs in exp2 domain (0.125*log2e folded into the score scale).
// Wave->q-tile map t = wave*16 + blockIdx.x makes block durations uniform.
#define LDP 72   // P row stride in u16 (144B, 16B-aligned)

__global__ __launch_bounds__(256, 2) void attn_kernel(
    const u16* __restrict__ Q, const u16* __restrict__ Kg, const u16* __restrict__ Vt,
    const int* __restrict__ mask, u16* __restrict__ O) {
    __shared__ __align__(16) u16 Psm[4][32 * LDP];
    int tid = threadIdx.x;
    int lane = tid & 63, wave = tid >> 6;
    int l15 = lane & 15, quad = lane >> 4;
    int bh = blockIdx.y; int b = bh >> 4, h = bh & 15;
    int t = wave * 16 + blockIdx.x;    // q-tile 0..63
    int q0 = t * 32;
    long tokBase = (long)b * S_;
    const float SCL = 0.125f * 1.4426950408889634f;  // exp2 domain

    const bf16x8 ones = {16256,16256,16256,16256,16256,16256,16256,16256}; // bf16 1.0

    bf16x8 aq[2][2];
    #pragma unroll
    for (int mt = 0; mt < 2; mt++) {
        const u16* qptr = Q + (tokBase + q0 + mt*16 + l15) * D_ + h * 64;
        aq[mt][0] = *(const bf16x8*)(qptr + quad * 8);
        aq[mt][1] = *(const bf16x8*)(qptr + 32 + quad * 8);
    }

    f32x4 o[2][4] = {};
    float mrow[2][4], lrow[2][4];
    #pragma unroll
    for (int mt = 0; mt < 2; mt++)
        #pragma unroll
        for (int i = 0; i < 4; i++) { mrow[mt][i] = -1e30f; lrow[mt][i] = 0.f; }

    u16* Pw = Psm[wave];
    const int* mb = mask + b * S_;
    int ktiles = t / 2 + 1;

    for (int kt = 0; kt < ktiles; kt++) {
        int k0 = kt * 64;
        // K,V fragments straight from global (L2-served; no barriers)
        bf16x8 kb[4][2], vb[4][2];
        #pragma unroll
        for (int nt = 0; nt < 4; nt++) {
            const u16* kp = Kg + (tokBase + k0 + nt*16 + l15) * D_ + h * 64;
            kb[nt][0] = *(const bf16x8*)(kp + quad * 8);
            kb[nt][1] = *(const bf16x8*)(kp + 32 + quad * 8);
        }
        #pragma unroll
        for (int d = 0; d < 4; d++) {
            const u16* vp = Vt + ((long)bh * 64 + d*16 + l15) * S_ + k0;
            vb[d][0] = *(const bf16x8*)(vp + quad * 8);
            vb[d][1] = *(const bf16x8*)(vp + 32 + quad * 8);
        }

        f32x4 s[2][4] = {};
        #pragma unroll
        for (int nt = 0; nt < 4; nt++) {
            s[0][nt] = __builtin_amdgcn_mfma_f32_16x16x32_bf16(aq[0][0], kb[nt][0], s[0][nt], 0,0,0);
            s[0][nt] = __builtin_amdgcn_mfma_f32_16x16x32_bf16(aq[0][1], kb[nt][1], s[0][nt], 0,0,0);
            s[1][nt] = __builtin_amdgcn_mfma_f32_16x16x32_bf16(aq[1][0], kb[nt][0], s[1][nt], 0,0,0);
            s[1][nt] = __builtin_amdgcn_mfma_f32_16x16x32_bf16(aq[1][1], kb[nt][1], s[1][nt], 0,0,0);
        }

        int mk = 0;
        #pragma unroll
        for (int nt = 0; nt < 4; nt++)
            if (mb[k0 + nt*16 + l15] != 0) mk |= (1 << nt);

        float alpha8[2][4];
        #pragma unroll
        for (int mt = 0; mt < 2; mt++) {
            #pragma unroll
            for (int i = 0; i < 4; i++) {
                int qq = q0 + mt*16 + quad*4 + i;
                float v[4], vmax = -1e30f;
                #pragma unroll
                for (int nt = 0; nt < 4; nt++) {
                    int kc = k0 + nt*16 + l15;
                    v[nt] = (kc <= qq && ((mk >> nt) & 1)) ? s[mt][nt][i] * SCL : -1e30f;
                    vmax = fmaxf(vmax, v[nt]);
                }
                #pragma unroll
                for (int mm = 1; mm < 16; mm <<= 1)
                    vmax = fmaxf(vmax, __shfl_xor(vmax, mm));
                float mnew = fmaxf(mrow[mt][i], vmax);
                float alpha = exp2f(mrow[mt][i] - mnew);
                mrow[mt][i] = mnew;
                alpha8[mt][i] = alpha;
                lrow[mt][i] *= alpha;
                #pragma unroll
                for (int nt = 0; nt < 4; nt++)
                    Pw[(mt*16 + quad*4 + i) * LDP + nt*16 + l15] = f2bf(exp2f(v[nt] - mnew));
                #pragma unroll
                for (int d = 0; d < 4; d++) o[mt][d][i] *= alpha;
            }
        }
        // same-wave P write -> read ordering
        asm volatile("s_waitcnt lgkmcnt(0)" ::: "memory");

        f32x4 osum[2] = {};
        #pragma unroll
        for (int half = 0; half < 2; half++) {
            bf16x8 ap0 = *(const bf16x8*)&Pw[l15 * LDP + half*32 + quad*8];
            bf16x8 ap1 = *(const bf16x8*)&Pw[(16 + l15) * LDP + half*32 + quad*8];
            #pragma unroll
            for (int d = 0; d < 4; d++) {
                o[0][d] = __builtin_amdgcn_mfma_f32_16x16x32_bf16(ap0, vb[d][half], o[0][d], 0,0,0);
                o[1][d] = __builtin_amdgcn_mfma_f32_16x16x32_bf16(ap1, vb[d][half], o[1][d], 0,0,0);
            }
            osum[0] = __builtin_amdgcn_mfma_f32_16x16x32_bf16(ap0, ones, osum[0], 0,0,0);
            osum[1] = __builtin_amdgcn_mfma_f32_16x16x32_bf16(ap1, ones, osum[1], 0,0,0);
        }
        #pragma unroll
        for (int mt = 0; mt < 2; mt++)
            #pragma unroll
            for (int i = 0; i < 4; i++)
                lrow[mt][i] += osum[mt][i];
        (void)alpha8;
    }

    #pragma unroll
    for (int mt = 0; mt < 2; mt++) {
        #pragma unroll
        for (int i = 0; i < 4; i++) {
            float inv = 1.f / lrow[mt][i];
            long r = tokBase + q0 + mt*16 + quad*4 + i;
            #pragma unroll
            for (int d = 0; d < 4; d++)
                O[r * D_ + h*64 + d*16 + l15] = f2bf(o[mt][d][i] * inv);
        }
    }
}

// ------------------------------------------------- launch
extern "C" void kernel_launch(void* const* d_in, const int* in_sizes, int n_in,
                              void* d_out, int out_size, void* d_ws, size_t ws_size,
                              hipStream_t stream) {
    const float* x    = (const float*)d_in[0];
    const int*   am   = (const int*)d_in[1];
    const float* ln1a = (const float*)d_in[2];
    const float* ln1b = (const float*)d_in[3];
    const float* ln2a = (const float*)d_in[4];
    const float* ln2b = (const float*)d_in[5];
    const float* wq   = (const float*)d_in[6];
    const float* wk   = (const float*)d_in[7];
    const float* wv   = (const float*)d_in[8];
    const float* wo   = (const float*)d_in[9];
    const float* w1   = (const float*)d_in[10];
    const float* b1   = (const float*)d_in[11];
    const float* w2   = (const float*)d_in[12];
    const float* b2   = (const float*)d_in[13];
    float* out = (float*)d_out;

    // Workspace: 72 MB, liveness-overlapped 16MB slots.
    char* ws = (char*)d_ws;
    const size_t MB16 = (size_t)16 * 1024 * 1024;
    u16* y1      = (u16*)(ws + 0 * MB16);   // LN1 out -> y2 (LN2 out)
    u16* q       = (u16*)(ws + 1 * MB16);   // q -> w1t/w2t
    u16* k       = (u16*)(ws + 2 * MB16);   // k -> h (slots 2+3)
    u16* v       = (u16*)(ws + 3 * MB16);   // v -> ctx -> h
    u16* wqt     = (u16*)(ws + 4 * MB16 + 0 * (size_t)D_ * D_ * 2);
    u16* wkt     = (u16*)(ws + 4 * MB16 + 1 * (size_t)D_ * D_ * 2);
    u16* wvt     = (u16*)(ws + 4 * MB16 + 2 * (size_t)D_ * D_ * 2);
    u16* wot     = (u16*)(ws + 4 * MB16 + 3 * (size_t)D_ * D_ * 2);
    u16* y2      = y1;                       // after QKV
    u16* w1t     = q;                        // after attn (8 MB)
    u16* w2t     = q + (size_t)D_ * DFF;     // after attn (8 MB)
    u16* h_chunk = k;                        // after Wo GEMM: 32 MB (slots 2+3)
    u16* ctx     = v;                        // after transpose_v
    u16*   vt  = (u16*)d_out;                // d_out scratch; dead after attn
    float* x1f = out;                        // x + ctx@Wo

    dim3 tb(32, 8);
    transpose_f2b<<<dim3(D_/32, D_/32), tb, 0, stream>>>(wq, wqt, D_, D_);
    transpose_f2b<<<dim3(D_/32, D_/32), tb, 0, stream>>>(wk, wkt, D_, D_);
    transpose_f2b<<<dim3(D_/32, D_/32), tb, 0, stream>>>(wv, wvt, D_, D_);
    transpose_f2b<<<dim3(D_/32, D_/32), tb, 0, stream>>>(wo, wot, D_, D_);

    ln_kernel<<<NT, 256, 0, stream>>>(x, ln1a, ln1b, y1);

    gemm_bt<<<dim3(D_/BN, NT/BM, 3), 256, 0, stream>>>(
        y1, wqt, wkt, wvt, q, k, v, NT, D_, D_, 0, nullptr, nullptr);

    transpose_v<<<dim3(S_/32, 2, B_*H_), tb, 0, stream>>>(v, vt);

    attn_kernel<<<dim3(16, B_*H_), 256, 0, stream>>>(q, k, vt, am, ctx);

    gemm_bt<<<dim3(D_/BN, NT/BM, 1), 256, 0, stream>>>(
        ctx, wot, wot, wot, x1f, x1f, x1f, NT, D_, D_, 1, nullptr, x);

    transpose_f2b<<<dim3(DFF/32, D_/32), tb, 0, stream>>>(w1, w1t, D_, DFF);
    transpose_f2b<<<dim3(D_/32, DFF/32), tb, 0, stream>>>(w2, w2t, DFF, D_);

    ln_kernel<<<NT, 256, 0, stream>>>(x1f, ln2a, ln2b, y2);

    // FFN, 2 chunks of 4096 rows (h: 32MB in slots 2+3)
    for (int mc = 0; mc < 2; mc++) {
        long m0 = (long)mc * 4096;
        gemm_bt<<<dim3(DFF/BN, 4096/BM, 1), 256, 0, stream>>>(
            y2 + m0 * D_, w1t, w1t, w1t, h_chunk, h_chunk, h_chunk,
            4096, DFF, D_, 2, b1, nullptr);
        gemm_bt<<<dim3(D_/BN, 4096/BM, 1), 256, 0, stream>>>(
            h_chunk, w2t, w2t, w2t, out + m0 * D_, out + m0 * D_, out + m0 * D_,
            4096, D_, DFF, 3, b2, x1f + m0 * D_);
    }
}

// Round 6
// 690.965 us; speedup vs baseline: 1.8341x; 1.2014x over previous
//
#include <hip/hip_runtime.h>
#include <math.h>

typedef unsigned short u16;
typedef unsigned int u32;
typedef __attribute__((ext_vector_type(4))) unsigned short u16x4;
typedef __attribute__((ext_vector_type(8))) short bf16x8;
typedef __attribute__((ext_vector_type(4))) float f32x4;

#define B_ 4
#define S_ 2048
#define D_ 1024
#define H_ 16
#define NT (B_*S_)
#define DFF 4096

static __device__ __forceinline__ float bf2f(u16 u) {
    return __uint_as_float(((u32)u) << 16);
}
static __device__ __forceinline__ u16 f2bf(float f) {
    u32 u = __float_as_uint(f);
    u32 r = (u + 0x7fffu + ((u >> 16) & 1u)) >> 16;
    return (u16)r;
}
// async 16B/lane global->LDS (LDS dest = wave-uniform base + lane*16)
static __device__ __forceinline__ void gload_lds16(const void* g, void* l) {
    __builtin_amdgcn_global_load_lds(
        (const __attribute__((address_space(1))) void*)g,
        (__attribute__((address_space(3))) void*)l, 16, 0, 0);
}

// ------------------------------------------------- transpose fp32 -> bf16
// batched x4 (same RxC for all): z picks src/dst
__global__ void transpose_f2b4(const float* __restrict__ s0, const float* __restrict__ s1,
                               const float* __restrict__ s2, const float* __restrict__ s3,
                               u16* __restrict__ d0, u16* __restrict__ d1,
                               u16* __restrict__ d2, u16* __restrict__ d3,
                               int R, int C) {
    const float* in = s0; u16* out = d0;
    if (blockIdx.z == 1) { in = s1; out = d1; }
    else if (blockIdx.z == 2) { in = s2; out = d2; }
    else if (blockIdx.z == 3) { in = s3; out = d3; }
    __shared__ float t[32][33];
    int c0 = blockIdx.x * 32, r0 = blockIdx.y * 32;
    int x = threadIdx.x, y = threadIdx.y;
    #pragma unroll
    for (int i = 0; i < 4; i++)
        t[y + i*8][x] = in[(long)(r0 + y + i*8) * C + c0 + x];
    __syncthreads();
    #pragma unroll
    for (int i = 0; i < 4; i++)
        out[(long)(c0 + y + i*8) * R + r0 + x] = f2bf(t[x][y + i*8]);
}

__global__ void transpose_f2b(const float* __restrict__ in, u16* __restrict__ out,
                              int R, int C) {
    __shared__ float t[32][33];
    int c0 = blockIdx.x * 32, r0 = blockIdx.y * 32;
    int x = threadIdx.x, y = threadIdx.y;
    #pragma unroll
    for (int i = 0; i < 4; i++)
        t[y + i*8][x] = in[(long)(r0 + y + i*8) * C + c0 + x];
    __syncthreads();
    #pragma unroll
    for (int i = 0; i < 4; i++)
        out[(long)(c0 + y + i*8) * R + r0 + x] = f2bf(t[x][y + i*8]);
}

// V bf16 [B*S][D] -> Vt bf16 [B*H][64][S]. grid (S/32, 2, B*H), block (32,8)
__global__ void transpose_v(const u16* __restrict__ V, u16* __restrict__ Vt) {
    __shared__ u16 t[32][33];
    int z = blockIdx.z; int b = z >> 4, h = z & 15;
    int s0 = blockIdx.x * 32, d0 = blockIdx.y * 32;
    int x = threadIdx.x, y = threadIdx.y;
    const u16* in = V + ((long)b * S_ + s0) * D_ + h * 64 + d0;
    #pragma unroll
    for (int i = 0; i < 4; i++)
        t[y + i*8][x] = in[(long)(y + i*8) * D_ + x];
    __syncthreads();
    u16* out = Vt + ((long)z * 64 + d0) * S_ + s0;
    #pragma unroll
    for (int i = 0; i < 4; i++)
        out[(long)(y + i*8) * S_ + x] = t[x][y + i*8];
}

// ------------------------------------------------- layernorm (fp32 in, bf16 out)
__global__ __launch_bounds__(256) void ln_kernel(
    const float* __restrict__ X, const float* __restrict__ alpha,
    const float* __restrict__ beta, u16* __restrict__ Y) {
    int row = blockIdx.x, tid = threadIdx.x;
    float4 xv = ((const float4*)(X + (long)row * D_))[tid];
    float v[4] = {xv.x, xv.y, xv.z, xv.w};
    float s = 0.f, ss = 0.f;
    #pragma unroll
    for (int i = 0; i < 4; i++) { s += v[i]; ss += v[i]*v[i]; }
    #pragma unroll
    for (int off = 32; off >= 1; off >>= 1) {
        s += __shfl_xor(s, off);
        ss += __shfl_xor(ss, off);
    }
    __shared__ float red[8];
    __shared__ float stats[2];
    int w = tid >> 6;
    if ((tid & 63) == 0) { red[w] = s; red[4 + w] = ss; }
    __syncthreads();
    if (tid == 0) {
        float S = red[0] + red[1] + red[2] + red[3];
        float SS = red[4] + red[5] + red[6] + red[7];
        float mean = S * (1.f / D_);
        float var = SS * (1.f / D_) - mean * mean;
        stats[0] = mean; stats[1] = rsqrtf(var + 1e-5f);
    }
    __syncthreads();
    float mean = stats[0], rstd = stats[1];
    float4 av = ((const float4*)alpha)[tid];
    float4 bv = ((const float4*)beta)[tid];
    u16x4 o;
    o[0] = f2bf((v[0] - mean) * rstd * av.x + bv.x);
    o[1] = f2bf((v[1] - mean) * rstd * av.y + bv.y);
    o[2] = f2bf((v[2] - mean) * rstd * av.z + bv.z);
    o[3] = f2bf((v[3] - mean) * rstd * av.w + bv.w);
    *(u16x4*)(Y + (long)row * D_ + tid * 4) = o;
}

// ------------------------------------------------- GEMM (bf16 A, bf16 B^T)
// m97 recipe: unpadded [row][64] LDS tiles staged via global_load_lds x16.
// mode 0: bf16 store; 1: fp32 acc+resid; 2: bf16 gelu(acc+bias); 3: fp32 acc+bias+resid
#define BM 128
#define BN 128
#define BK 64

__global__ __launch_bounds__(256, 2) void gemm_bt(
    const u16* __restrict__ A,
    const u16* __restrict__ Bt0, const u16* __restrict__ Bt1, const u16* __restrict__ Bt2,
    void* __restrict__ C0, void* __restrict__ C1, void* __restrict__ C2,
    int M, int N, int K, int mode,
    const float* __restrict__ bias, const float* __restrict__ resid) {
    const u16* Bt = Bt0; void* C = C0;
    if (blockIdx.z == 1) { Bt = Bt1; C = C1; }
    else if (blockIdx.z == 2) { Bt = Bt2; C = C2; }

    __shared__ __align__(16) u16 Asm[BM * BK];
    __shared__ __align__(16) u16 Bsm[BN * BK];

    int tid = threadIdx.x;
    int lane = tid & 63, wave = tid >> 6;
    int l15 = lane & 15, quad = lane >> 4;
    int wm = wave & 1, wn = wave >> 1;
    long tm0 = (long)blockIdx.y * BM, tn0 = (long)blockIdx.x * BN;

    int srow = lane >> 3;          // 0..7 within chunk
    int scol = (lane & 7) * 8;     // u16 col offset

    f32x4 acc[4][4] = {};

    for (int k0 = 0; k0 < K; k0 += BK) {
        __syncthreads();
        #pragma unroll
        for (int c = 0; c < 4; c++) {
            int chunk = wave * 4 + c;          // 0..15
            int row = chunk * 8 + srow;        // 0..127
            gload_lds16(&A[(tm0 + row) * (long)K + k0 + scol], &Asm[chunk * 512]);
            gload_lds16(&Bt[(tn0 + row) * (long)K + k0 + scol], &Bsm[chunk * 512]);
        }
        __syncthreads();   // drains vmcnt(0): LDS tiles complete
        #pragma unroll
        for (int ks = 0; ks < 2; ks++) {
            bf16x8 af[4], bfm[4];
            #pragma unroll
            for (int mt = 0; mt < 4; mt++)
                af[mt] = *(const bf16x8*)&Asm[(wm*64 + mt*16 + l15) * BK + ks*32 + quad*8];
            #pragma unroll
            for (int nt = 0; nt < 4; nt++)
                bfm[nt] = *(const bf16x8*)&Bsm[(wn*64 + nt*16 + l15) * BK + ks*32 + quad*8];
            #pragma unroll
            for (int mt = 0; mt < 4; mt++)
                #pragma unroll
                for (int nt = 0; nt < 4; nt++)
                    acc[mt][nt] = __builtin_amdgcn_mfma_f32_16x16x32_bf16(
                        af[mt], bfm[nt], acc[mt][nt], 0, 0, 0);
        }
    }

    #pragma unroll
    for (int mt = 0; mt < 4; mt++) {
        #pragma unroll
        for (int nt = 0; nt < 4; nt++) {
            #pragma unroll
            for (int i = 0; i < 4; i++) {
                long r = tm0 + wm*64 + mt*16 + quad*4 + i;
                long cn = tn0 + wn*64 + nt*16 + l15;
                long idx = r * N + cn;
                float val = acc[mt][nt][i];
                if (mode == 0) {
                    ((u16*)C)[idx] = f2bf(val);
                } else if (mode == 1) {
                    ((float*)C)[idx] = val + resid[idx];
                } else if (mode == 2) {
                    val += bias[cn];
                    val = 0.5f * val * (1.0f + erff(val * 0.70710678118654752f));
                    ((u16*)C)[idx] = f2bf(val);
                } else {
                    ((float*)C)[idx] = val + bias[cn] + resid[idx];
                }
            }
        }
    }
}

// ------------------------------------------------- attention
// Wave-autonomous, ZERO barriers, fixed-max exp2 softmax (no cross-lane ops,
// no online rescale — denominator comes from the all-ones MFMA accumulated
// across all tiles; o/l is invariant to the fixed max M).
// Balance: wave j = wave*8 + blockIdx.y handles q-tiles j and 63-j (33-34
// iters for every wave). Grid (bh, 8): all 8 blocks of a head land on the
// same XCD (linear id = bh + 64*by -> XCD = bh%8) so K/V stay in that L2.
#define LDP 72   // P row stride in u16 (144B, 16B-aligned)

__global__ __launch_bounds__(256, 2) void attn_kernel(
    const u16* __restrict__ Q, const u16* __restrict__ Kg, const u16* __restrict__ Vt,
    const int* __restrict__ mask, u16* __restrict__ O) {
    __shared__ __align__(16) u16 Psm[4][32 * LDP];
    int tid = threadIdx.x;
    int lane = tid & 63, wave = tid >> 6;
    int l15 = lane & 15, quad = lane >> 4;
    int bh = blockIdx.x; int b = bh >> 4, h = bh & 15;
    int j = wave * 8 + blockIdx.y;     // 0..31
    long tokBase = (long)b * S_;
    const float SCL = 0.125f * 1.4426950408889634f;  // exp2 domain
    const float MMAX = 20.0f;                        // fixed softmax shift

    const bf16x8 ones = {16256,16256,16256,16256,16256,16256,16256,16256}; // bf16 1.0
    u16* Pw = Psm[wave];
    const int* mb = mask + b * S_;

    #pragma unroll
    for (int half = 0; half < 2; half++) {
        int t = half ? (63 - j) : j;   // q-tile index 0..63
        int q0 = t * 32;

        bf16x8 aq[2][2];
        #pragma unroll
        for (int mt = 0; mt < 2; mt++) {
            const u16* qptr = Q + (tokBase + q0 + mt*16 + l15) * D_ + h * 64;
            aq[mt][0] = *(const bf16x8*)(qptr + quad * 8);
            aq[mt][1] = *(const bf16x8*)(qptr + 32 + quad * 8);
        }

        f32x4 o[2][4] = {};
        f32x4 lacc[2] = {};
        int ktiles = t / 2 + 1;

        for (int kt = 0; kt < ktiles; kt++) {
            int k0 = kt * 64;
            bf16x8 kb[4][2], vb[4][2];
            #pragma unroll
            for (int nt = 0; nt < 4; nt++) {
                const u16* kp = Kg + (tokBase + k0 + nt*16 + l15) * D_ + h * 64;
                kb[nt][0] = *(const bf16x8*)(kp + quad * 8);
                kb[nt][1] = *(const bf16x8*)(kp + 32 + quad * 8);
            }
            #pragma unroll
            for (int d = 0; d < 4; d++) {
                const u16* vp = Vt + ((long)bh * 64 + d*16 + l15) * S_ + k0;
                vb[d][0] = *(const bf16x8*)(vp + quad * 8);
                vb[d][1] = *(const bf16x8*)(vp + 32 + quad * 8);
            }

            f32x4 s[2][4] = {};
            #pragma unroll
            for (int nt = 0; nt < 4; nt++) {
                s[0][nt] = __builtin_amdgcn_mfma_f32_16x16x32_bf16(aq[0][0], kb[nt][0], s[0][nt], 0,0,0);
                s[0][nt] = __builtin_amdgcn_mfma_f32_16x16x32_bf16(aq[0][1], kb[nt][1], s[0][nt], 0,0,0);
                s[1][nt] = __builtin_amdgcn_mfma_f32_16x16x32_bf16(aq[1][0], kb[nt][0], s[1][nt], 0,0,0);
                s[1][nt] = __builtin_amdgcn_mfma_f32_16x16x32_bf16(aq[1][1], kb[nt][1], s[1][nt], 0,0,0);
            }

            int mk = 0;
            #pragma unroll
            for (int nt = 0; nt < 4; nt++)
                if (mb[k0 + nt*16 + l15] != 0) mk |= (1 << nt);

            #pragma unroll
            for (int mt = 0; mt < 2; mt++) {
                #pragma unroll
                for (int i = 0; i < 4; i++) {
                    int qq = q0 + mt*16 + quad*4 + i;
                    #pragma unroll
                    for (int nt = 0; nt < 4; nt++) {
                        int kc = k0 + nt*16 + l15;
                        float p = exp2f(fmaf(s[mt][nt][i], SCL, -MMAX));
                        p = (kc <= qq && ((mk >> nt) & 1)) ? p : 0.f;
                        Pw[(mt*16 + quad*4 + i) * LDP + nt*16 + l15] = f2bf(p);
                    }
                }
            }
            // same-wave P write -> read ordering (P is wave-private)
            asm volatile("s_waitcnt lgkmcnt(0)" ::: "memory");

            #pragma unroll
            for (int hv = 0; hv < 2; hv++) {
                bf16x8 ap0 = *(const bf16x8*)&Pw[l15 * LDP + hv*32 + quad*8];
                bf16x8 ap1 = *(const bf16x8*)&Pw[(16 + l15) * LDP + hv*32 + quad*8];
                #pragma unroll
                for (int d = 0; d < 4; d++) {
                    o[0][d] = __builtin_amdgcn_mfma_f32_16x16x32_bf16(ap0, vb[d][hv], o[0][d], 0,0,0);
                    o[1][d] = __builtin_amdgcn_mfma_f32_16x16x32_bf16(ap1, vb[d][hv], o[1][d], 0,0,0);
                }
                lacc[0] = __builtin_amdgcn_mfma_f32_16x16x32_bf16(ap0, ones, lacc[0], 0,0,0);
                lacc[1] = __builtin_amdgcn_mfma_f32_16x16x32_bf16(ap1, ones, lacc[1], 0,0,0);
            }
        }

        #pragma unroll
        for (int mt = 0; mt < 2; mt++) {
            #pragma unroll
            for (int i = 0; i < 4; i++) {
                float inv = 1.f / lacc[mt][i];
                long r = tokBase + q0 + mt*16 + quad*4 + i;
                #pragma unroll
                for (int d = 0; d < 4; d++)
                    O[r * D_ + h*64 + d*16 + l15] = f2bf(o[mt][d][i] * inv);
            }
        }
    }
}

// ------------------------------------------------- launch
extern "C" void kernel_launch(void* const* d_in, const int* in_sizes, int n_in,
                              void* d_out, int out_size, void* d_ws, size_t ws_size,
                              hipStream_t stream) {
    const float* x    = (const float*)d_in[0];
    const int*   am   = (const int*)d_in[1];
    const float* ln1a = (const float*)d_in[2];
    const float* ln1b = (const float*)d_in[3];
    const float* ln2a = (const float*)d_in[4];
    const float* ln2b = (const float*)d_in[5];
    const float* wq   = (const float*)d_in[6];
    const float* wk   = (const float*)d_in[7];
    const float* wv   = (const float*)d_in[8];
    const float* wo   = (const float*)d_in[9];
    const float* w1   = (const float*)d_in[10];
    const float* b1   = (const float*)d_in[11];
    const float* w2   = (const float*)d_in[12];
    const float* b2   = (const float*)d_in[13];
    float* out = (float*)d_out;

    // Workspace: 72 MB, liveness-overlapped 16MB slots.
    char* ws = (char*)d_ws;
    const size_t MB16 = (size_t)16 * 1024 * 1024;
    u16* y1      = (u16*)(ws + 0 * MB16);   // LN1 out -> y2 (LN2 out)
    u16* q       = (u16*)(ws + 1 * MB16);   // q -> w1t/w2t
    u16* k       = (u16*)(ws + 2 * MB16);   // k -> h (slots 2+3)
    u16* v       = (u16*)(ws + 3 * MB16);   // v -> ctx -> h(hi)
    u16* wqt     = (u16*)(ws + 4 * MB16 + 0 * (size_t)D_ * D_ * 2);
    u16* wkt     = (u16*)(ws + 4 * MB16 + 1 * (size_t)D_ * D_ * 2);
    u16* wvt     = (u16*)(ws + 4 * MB16 + 2 * (size_t)D_ * D_ * 2);
    u16* wot     = (u16*)(ws + 4 * MB16 + 3 * (size_t)D_ * D_ * 2);
    u16* y2      = y1;                       // after QKV
    u16* w1t     = q;                        // after attn (8 MB)
    u16* w2t     = q + (size_t)D_ * DFF;     // after attn (8 MB)
    u16* h_full  = k;                        // after Wo GEMM: 32 MB (slots 2+3)
    u16* ctx     = v;                        // after transpose_v
    u16*   vt  = (u16*)d_out;                // d_out scratch; dead after attn
    float* x1f = out;                        // x + ctx@Wo

    dim3 tb(32, 8);
    transpose_f2b4<<<dim3(D_/32, D_/32, 4), tb, 0, stream>>>(
        wq, wk, wv, wo, wqt, wkt, wvt, wot, D_, D_);

    ln_kernel<<<NT, 256, 0, stream>>>(x, ln1a, ln1b, y1);

    gemm_bt<<<dim3(D_/BN, NT/BM, 3), 256, 0, stream>>>(
        y1, wqt, wkt, wvt, q, k, v, NT, D_, D_, 0, nullptr, nullptr);

    transpose_v<<<dim3(S_/32, 2, B_*H_), tb, 0, stream>>>(v, vt);

    attn_kernel<<<dim3(B_*H_, 8), 256, 0, stream>>>(q, k, vt, am, ctx);

    gemm_bt<<<dim3(D_/BN, NT/BM, 1), 256, 0, stream>>>(
        ctx, wot, wot, wot, x1f, x1f, x1f, NT, D_, D_, 1, nullptr, x);

    transpose_f2b<<<dim3(DFF/32, D_/32), tb, 0, stream>>>(w1, w1t, D_, DFF);
    transpose_f2b<<<dim3(D_/32, DFF/32), tb, 0, stream>>>(w2, w2t, DFF, D_);

    ln_kernel<<<NT, 256, 0, stream>>>(x1f, ln2a, ln2b, y2);

    // FFN, unchunked (h: 32MB in slots 2+3; W2 grid 512 blocks not 256)
    gemm_bt<<<dim3(DFF/BN, NT/BM, 1), 256, 0, stream>>>(
        y2, w1t, w1t, w1t, h_full, h_full, h_full, NT, DFF, D_, 2, b1, nullptr);
    gemm_bt<<<dim3(D_/BN, NT/BM, 1), 256, 0, stream>>>(
        h_full, w2t, w2t, w2t, out, out, out, NT, D_, DFF, 3, b2, x1f);
}